// Round 16
// baseline (215.542 us; speedup 1.0000x reference)
//
#include <hip/hip_runtime.h>
#include <hip/hip_bf16.h>
#include <stdint.h>

#define B_ 2
#define T_ 2048
#define C_ 2048
#define NH_ 16
#define NKVH_ 4
#define HS_ 128
#define QKV_ 3072
#define NTOK_ 4096

typedef __attribute__((ext_vector_type(4))) float f32x4;
typedef __attribute__((ext_vector_type(16))) float f32x16;
typedef __attribute__((ext_vector_type(8))) short s16x8;

__device__ __forceinline__ short f2bf(float f) {
    union { float f; unsigned u; } v; v.f = f;
    unsigned r = v.u + 0x7FFFu + ((v.u >> 16) & 1u);
    return (short)(r >> 16);
}

__device__ __forceinline__ void async16(const void* g, void* l) {
    __builtin_amdgcn_global_load_lds(
        (const __attribute__((address_space(1))) void*)g,
        (__attribute__((address_space(3))) void*)l, 16, 0, 0);
}

// ---------------- fused prep: cast x->bf16 + transcast W_attn + transcast W_proj ----------------
__device__ __forceinline__ void transcast_body(const float* __restrict__ W, short* __restrict__ WT,
                                               int Kd, int Nd, int k0, int n0, int tid) {
    __shared__ float tile[64][65];
    int cl = tid & 63, rw = tid >> 6;
    for (int it = 0; it < 16; ++it) {
        int r = it * 4 + rw;
        tile[r][cl] = W[(size_t)(k0 + r) * Nd + n0 + cl];
    }
    __syncthreads();
    for (int it = 0; it < 16; ++it) {
        int n = it * 4 + rw;
        WT[(size_t)(n0 + n) * Kd + k0 + cl] = f2bf(tile[cl][n]);
    }
}

__global__ void prep_kernel(const float* __restrict__ x, short* __restrict__ xb,
                            const float* __restrict__ Wa, short* __restrict__ WaT,
                            const float* __restrict__ Wp, short* __restrict__ WpT)
{
    int bid = blockIdx.x, tid = threadIdx.x;
    if (bid < 2048) {
        const int n8 = NTOK_ * C_ / 8;
        int i0 = bid * 512 + tid;
#pragma unroll
        for (int rep = 0; rep < 2; rep++) {
            int i = i0 + rep * 256;
            if (i >= n8) return;
            const float4* p = (const float4*)x + (size_t)i * 2;
            float4 a = p[0], b = p[1];
            short o[8] = { f2bf(a.x), f2bf(a.y), f2bf(a.z), f2bf(a.w),
                           f2bf(b.x), f2bf(b.y), f2bf(b.z), f2bf(b.w) };
            *(int4*)(xb + (size_t)i * 8) = *(const int4*)o;
        }
    } else if (bid < 3584) {
        int b2 = bid - 2048;                 // 1536 blocks = 32 x 48
        transcast_body(Wa, WaT, C_, QKV_, (b2 & 31) * 64, (b2 >> 5) * 64, tid);
    } else {
        int b2 = bid - 3584;                 // 1024 blocks = 32 x 32
        transcast_body(Wp, WpT, C_, C_, (b2 & 31) * 64, (b2 >> 5) * 64, tid);
    }
}

// ---------------- GEMM: A[M][K] bf16 x Bt[N][K] bf16 -> C[M][N] f32 + bias ----------------
__global__ __launch_bounds__(256, 2) void gemm_bt(
    const short* __restrict__ A, const short* __restrict__ Bt,
    const float* __restrict__ bias, float* __restrict__ Cc,
    int M, int N, int K)
{
    __shared__ short As[128 * 64];
    __shared__ short Bs[128 * 64];
    int tid = threadIdx.x;
    int w = tid >> 6, l = tid & 63;
    int lr = l & 15, lg = l >> 4;
    int bm = blockIdx.x, bn = blockIdx.y;
    int wm = (w >> 1) * 64, wn = (w & 1) * 64;
    f32x4 acc[4][4];
#pragma unroll
    for (int i = 0; i < 4; i++)
#pragma unroll
        for (int j = 0; j < 4; j++) { acc[i][j][0]=0.f; acc[i][j][1]=0.f; acc[i][j][2]=0.f; acc[i][j][3]=0.f; }
    int arow = l >> 3, acol = (l & 7) * 8;
    for (int k0 = 0; k0 < K; k0 += 64) {
#pragma unroll
        for (int i = 0; i < 4; i++) {
            int chunk = w * 4 + i;
            int row = chunk * 8 + arow;
            async16(A  + (size_t)(bm * 128 + row) * K + k0 + acol, (char*)As + chunk * 1024);
            async16(Bt + (size_t)(bn * 128 + row) * K + k0 + acol, (char*)Bs + chunk * 1024);
        }
        __syncthreads();
#pragma unroll
        for (int ks = 0; ks < 2; ks++) {
            s16x8 af[4], bf[4];
#pragma unroll
            for (int mi = 0; mi < 4; mi++)
                af[mi] = *(const s16x8*)&As[(wm + mi * 16 + lr) * 64 + ks * 32 + lg * 8];
#pragma unroll
            for (int ni = 0; ni < 4; ni++)
                bf[ni] = *(const s16x8*)&Bs[(wn + ni * 16 + lr) * 64 + ks * 32 + lg * 8];
#pragma unroll
            for (int mi = 0; mi < 4; mi++)
#pragma unroll
                for (int ni = 0; ni < 4; ni++)
                    acc[mi][ni] = __builtin_amdgcn_mfma_f32_16x16x32_bf16(af[mi], bf[ni], acc[mi][ni], 0, 0, 0);
        }
        __syncthreads();
    }
#pragma unroll
    for (int mi = 0; mi < 4; mi++) {
        int row = bm * 128 + wm + mi * 16 + lg * 4;
#pragma unroll
        for (int ni = 0; ni < 4; ni++) {
            int col = bn * 128 + wn + ni * 16 + lr;
            float bv = bias[col];
#pragma unroll
            for (int j = 0; j < 4; j++)
                Cc[(size_t)(row + j) * N + col] = acc[mi][ni][j] + bv;
        }
    }
}

// ---------------- Fused QKV GEMM: x_bf16 x W_attn^T + b, then RoPE + scatter in epilogue ----------
__global__ __launch_bounds__(256, 2) void gemm_qkv(
    const short* __restrict__ A, const short* __restrict__ Bt,
    const float* __restrict__ bias,
    const float* __restrict__ fcos, const float* __restrict__ fsin,
    short* __restrict__ Q, short* __restrict__ Kb, short* __restrict__ VT)
{
    __shared__ short As[128 * 64];
    __shared__ short Bs[128 * 64];
    const int K = C_;
    int tid = threadIdx.x;
    int w = tid >> 6, l = tid & 63;
    int lr = l & 15, lg = l >> 4;
    int bm = blockIdx.x, bn = blockIdx.y;
    int wm = (w >> 1) * 64, wn = (w & 1) * 64;
    f32x4 acc[4][4];
#pragma unroll
    for (int i = 0; i < 4; i++)
#pragma unroll
        for (int j = 0; j < 4; j++) { acc[i][j][0]=0.f; acc[i][j][1]=0.f; acc[i][j][2]=0.f; acc[i][j][3]=0.f; }
    int arow = l >> 3, acol = (l & 7) * 8;
    for (int k0 = 0; k0 < K; k0 += 64) {
#pragma unroll
        for (int i = 0; i < 4; i++) {
            int chunk = w * 4 + i;
            int row = chunk * 8 + arow;
            async16(A  + (size_t)(bm * 128 + row) * K + k0 + acol, (char*)As + chunk * 1024);
            async16(Bt + (size_t)(bn * 128 + row) * K + k0 + acol, (char*)Bs + chunk * 1024);
        }
        __syncthreads();
#pragma unroll
        for (int ks = 0; ks < 2; ks++) {
            s16x8 af[4], bf[4];
#pragma unroll
            for (int mi = 0; mi < 4; mi++)
                af[mi] = *(const s16x8*)&As[(wm + mi * 16 + lr) * 64 + ks * 32 + lg * 8];
#pragma unroll
            for (int ni = 0; ni < 4; ni++)
                bf[ni] = *(const s16x8*)&Bs[(wn + ni * 16 + lr) * 64 + ks * 32 + lg * 8];
#pragma unroll
            for (int mi = 0; mi < 4; mi++)
#pragma unroll
                for (int ni = 0; ni < 4; ni++)
                    acc[mi][ni] = __builtin_amdgcn_mfma_f32_16x16x32_bf16(af[mi], bf[ni], acc[mi][ni], 0, 0, 0);
        }
        __syncthreads();
    }
    // ---- fused epilogue ----
    int b = bm >> 4;                 // batch (block-uniform)
    int tt0 = (bm & 15) * 128 + wm;  // sequence pos base (+ mi*16 + lg*4 + j)
    const float qsc = 0.08838834764831845f; // 1/sqrt(128)
    if (bn < 20) {
        bool isQ = (bn < 16);
        short* Ob = isQ ? (Q + (size_t)(b * NH_ + bn) * T_ * HS_)
                        : (Kb + (size_t)(b * NKVH_ + (bn - 16)) * T_ * HS_);
        float sc = isQ ? qsc : 1.0f;
#pragma unroll
        for (int ni = 0; ni < 4; ni++) {
            int d = wn + ni * 16 + lr;           // 0..127 within head
            int i = d >> 1;
            float ssign = (d & 1) ? 1.0f : -1.0f;
            float bv = bias[bn * 128 + d];
#pragma unroll
            for (int mi = 0; mi < 4; mi++) {
                int ttb = tt0 + mi * 16 + lg * 4;
#pragma unroll
                for (int j = 0; j < 4; j++) {
                    float v = acc[mi][ni][j] + bv;
                    float prt = __shfl_xor(v, 1);
                    int tt = ttb + j;
                    float c = fcos[tt * 64 + i], s = fsin[tt * 64 + i];
                    float outv = (v * c + ssign * prt * s) * sc;
                    Ob[(size_t)tt * HS_ + d] = f2bf(outv);
                }
            }
        }
    } else {
        int g = bn - 20;
        short* Vb = VT + (size_t)(b * NKVH_ + g) * HS_ * T_;
#pragma unroll
        for (int ni = 0; ni < 4; ni++) {
            int d = wn + ni * 16 + lr;
            float bv = bias[bn * 128 + d];
#pragma unroll
            for (int mi = 0; mi < 4; mi++) {
                int ttb = tt0 + mi * 16 + lg * 4;
                short pk4[4];
#pragma unroll
                for (int j = 0; j < 4; j++) pk4[j] = f2bf(acc[mi][ni][j] + bv);
                *(int2*)(Vb + (size_t)d * T_ + ttb) = *(const int2*)pk4;
            }
        }
    }
}

// ---------------- Flash attention — swapped-QK^T 32x32, 8-wave blocks, KVBLK=128 ----------------
// grid: (B*NH=32, 8 Q-supertiles), block 512 (8 waves x 32 q-rows = 256-row q-tile), 1 block/CU.
// ROUND-15 LESSON: co-residency overlap is weak (~10%); per-tile FIXED costs dominate ->
// amortize them: KVBLK=128 halves barriers/tile-work; 8 waves share each staged tile (staging
// per wave-work halves). LDS = K[2][128x256B] + V[2][128x256B] = 128KB (1 block/CU).
// All per-wave math identical to the proven round-15 code with s-ranges doubled:
// sacc[4], w01/w23[4][4]; PV mux formulas (sb=sc>>1, k0=(2sc)&3) hold for sc 0..7.
// K and V LDS rows are both 256B now -> same bit-8 row XOR swizzle for staging and reads.
// launch_bounds(512,2): VGPR cap 256 (est ~200, no spill). grid.x MUST be 32 (b=bh>>4).
__global__ __launch_bounds__(512, 2) void attn_kernel(
    const short* __restrict__ Qg, const short* __restrict__ Kg,
    const short* __restrict__ VTg, short* __restrict__ Y)
{
    __shared__ short Ks[2][128 * 128];   // [buf][s][d], 256B rows, XOR ((row&7)<<4)
    __shared__ short VTs[2][128 * 128];  // [buf][d][s], 256B rows, XOR ((row&7)<<4)
    int tid = threadIdx.x, w = tid >> 6, l = tid & 63;
    int l31 = l & 31, hi = l >> 5;
    int Q8 = 7 - (int)blockIdx.y;        // LPT: longest first
    int bh = blockIdx.x;
    int b = bh >> 4, h = bh & 15, g = h >> 2;
    const short* Qb = Qg + (size_t)(b * NH_ + h) * T_ * HS_;
    const short* Kb = Kg + (size_t)(b * NKVH_ + g) * T_ * HS_;
    const short* Vb = VTg + (size_t)(b * NKVH_ + g) * HS_ * T_;

    // staging: waves 0-3 stage K (8 chunks each), waves 4-7 stage V (8 chunks each)
    auto STAGE = [&](int st, int buf) {
        if (w < 4) {
#pragma unroll
            for (int i = 0; i < 8; i++) {
                int chunk = w * 8 + i;
                int poff = chunk * 1024 + l * 16;
                int qoffk = poff ^ (((poff >> 8) & 7) << 4);
                async16(Kb + (size_t)(st * 128 + (qoffk >> 8)) * HS_ + ((qoffk & 255) >> 1),
                        (char*)&Ks[buf][0] + chunk * 1024);
            }
        } else {
#pragma unroll
            for (int i = 0; i < 8; i++) {
                int chunk = (w - 4) * 8 + i;
                int poff = chunk * 1024 + l * 16;
                int qoffv = poff ^ (((poff >> 8) & 7) << 4);
                async16(Vb + (size_t)(qoffv >> 8) * T_ + st * 128 + ((qoffv & 255) >> 1),
                        (char*)&VTs[buf][0] + chunk * 1024);
            }
        }
    };

    int qw = Q8 * 256 + w * 32;      // wave's first q-row
    int qglob = qw + l31;            // this lane's q-row

    s16x8 qf[8];
#pragma unroll
    for (int dc = 0; dc < 8; dc++)
        qf[dc] = *(const s16x8*)(Qb + (size_t)qglob * HS_ + dc * 16 + hi * 8);

    f32x16 oacc[4];
#pragma unroll
    for (int db = 0; db < 4; db++)
#pragma unroll
        for (int i = 0; i < 16; i++) oacc[db][i] = 0.f;
    float m = -1e30f, lsum = 0.f;
    int nst = 2 * Q8 + 2;            // 128-row KV tiles covering rows 0..Q8*256+255

    STAGE(0, 0);
    __syncthreads();
    int cur = 0;

    for (int st = 0; st < nst; ++st) {
        if (st + 1 < nst) STAGE(st + 1, cur ^ 1);   // prefetch flies under compute
        if (st * 128 <= qw) {                       // skip fully-masked tiles (wave-uniform)
            const char* KsC = (const char*)&Ks[cur][0];
            const char* VsC = (const char*)&VTs[cur][0];

            // S^T over 128 s-rows: sacc[sb], sb 0..3; 2 acc chains per s-block
            f32x16 sacc[4];
            __builtin_amdgcn_s_setprio(1);
#pragma unroll
            for (int sb = 0; sb < 4; sb++) {
                f32x16 a0, a1;
#pragma unroll
                for (int i = 0; i < 16; i++) { a0[i] = 0.f; a1[i] = 0.f; }
#pragma unroll
                for (int dc = 0; dc < 4; dc++) {
                    int lo0 = (sb * 32 + l31) * 256 + dc * 32 + hi * 16;
                    int po0 = lo0 ^ (((lo0 >> 8) & 7) << 4);
                    s16x8 kf0 = *(const s16x8*)(KsC + po0);
                    a0 = __builtin_amdgcn_mfma_f32_32x32x16_bf16(kf0, qf[dc], a0, 0, 0, 0);
                    int lo1 = (sb * 32 + l31) * 256 + (dc + 4) * 32 + hi * 16;
                    int po1 = lo1 ^ (((lo1 >> 8) & 7) << 4);
                    s16x8 kf1 = *(const s16x8*)(KsC + po1);
                    a1 = __builtin_amdgcn_mfma_f32_32x32x16_bf16(kf1, qf[dc + 4], a1, 0, 0, 0);
                }
#pragma unroll
                for (int i = 0; i < 16; i++) a0[i] += a1[i];
                sacc[sb] = a0;
            }
            __builtin_amdgcn_s_setprio(0);
            // causal mask (boundary tiles only)
            if (st * 128 + 127 > qw) {
#pragma unroll
                for (int sb = 0; sb < 4; sb++)
#pragma unroll
                    for (int r = 0; r < 16; r++) {
                        int s = st * 128 + sb * 32 + (r & 3) + 8 * (r >> 2) + 4 * hi;
                        if (s > qglob) sacc[sb][r] = -1e30f;
                    }
            }
            // row max: local fmax + 1 cross-half merge
            float tm = -1e30f;
#pragma unroll
            for (int sb = 0; sb < 4; sb++)
#pragma unroll
                for (int r = 0; r < 16; r++) tm = fmaxf(tm, sacc[sb][r]);
            tm = fmaxf(tm, __shfl_xor(tm, 32));
            // exact defer-rescale
            if (__any(tm > m)) {
                float mn = fmaxf(m, tm);
                float corr = __expf(m - mn);
                m = mn; lsum *= corr;
#pragma unroll
                for (int db = 0; db < 4; db++)
#pragma unroll
                    for (int r = 0; r < 16; r++) oacc[db][r] *= corr;
            }
            // P = exp(S^T - m), packed in-register
            unsigned w01[4][4], w23[4][4];
#pragma unroll
            for (int sb = 0; sb < 4; sb++)
#pragma unroll
                for (int k = 0; k < 4; k++) {
                    float p0 = __expf(sacc[sb][4 * k]     - m);
                    float p1 = __expf(sacc[sb][4 * k + 1] - m);
                    float p2 = __expf(sacc[sb][4 * k + 2] - m);
                    float p3 = __expf(sacc[sb][4 * k + 3] - m);
                    lsum += (p0 + p1) + (p2 + p3);
                    w01[sb][k] = (unsigned)(unsigned short)f2bf(p0) | ((unsigned)(unsigned short)f2bf(p1) << 16);
                    w23[sb][k] = (unsigned)(unsigned short)f2bf(p2) | ((unsigned)(unsigned short)f2bf(p3) << 16);
                }
            // O^T += V^T · P ; PV B-operand via cross-half shfl
            __builtin_amdgcn_s_setprio(1);
#pragma unroll
            for (int sc = 0; sc < 8; sc++) {
                const int sb = sc >> 1;
                const int k0 = (2 * sc) & 3, k1 = k0 + 1;
                unsigned ownA = hi ? w01[sb][k1] : w01[sb][k0];
                unsigned ownB = hi ? w23[sb][k1] : w23[sb][k0];
                unsigned sndA = hi ? w01[sb][k0] : w01[sb][k1];
                unsigned sndB = hi ? w23[sb][k0] : w23[sb][k1];
                unsigned rcvA = (unsigned)__shfl_xor((int)sndA, 32);
                unsigned rcvB = (unsigned)__shfl_xor((int)sndB, 32);
                unsigned uu[4];
                uu[0] = hi ? rcvA : ownA;
                uu[1] = hi ? rcvB : ownB;
                uu[2] = hi ? ownA : rcvA;
                uu[3] = hi ? ownB : rcvB;
                s16x8 pf = *(const s16x8*)uu;
#pragma unroll
                for (int db = 0; db < 4; db++) {
                    int lo = (db * 32 + l31) * 256 + sc * 32 + hi * 16;
                    int po = lo ^ (((lo >> 8) & 7) << 4);
                    s16x8 vf = *(const s16x8*)(VsC + po);
                    oacc[db] = __builtin_amdgcn_mfma_f32_32x32x16_bf16(vf, pf, oacc[db], 0, 0, 0);
                }
            }
            __builtin_amdgcn_s_setprio(0);
        }
        __syncthreads();   // implicit vmcnt(0): prefetch landed; buf[cur] free
        cur ^= 1;
    }

    lsum += __shfl_xor(lsum, 32);
    float inv = 1.0f / lsum;
    short* Yrow = Y + (size_t)(b * T_ + qglob) * C_ + h * 128;
#pragma unroll
    for (int db = 0; db < 4; db++)
#pragma unroll
        for (int pr = 0; pr < 8; pr++) {
            unsigned u0 = (unsigned short)f2bf(oacc[db][2 * pr] * inv);
            unsigned u1 = (unsigned short)f2bf(oacc[db][2 * pr + 1] * inv);
            int d = db * 32 + ((2 * pr) & 3) + 8 * (pr >> 1) + 4 * hi;
            *(unsigned*)(Yrow + d) = u0 | (u1 << 16);
        }
}

extern "C" void kernel_launch(void* const* d_in, const int* in_sizes, int n_in,
                              void* d_out, int out_size, void* d_ws, size_t ws_size,
                              hipStream_t stream)
{
    const float* x      = (const float*)d_in[0];
    const float* fcos   = (const float*)d_in[1];
    const float* fsin   = (const float*)d_in[2];
    const float* W_attn = (const float*)d_in[3];
    const float* b_attn = (const float*)d_in[4];
    const float* W_proj = (const float*)d_in[5];
    const float* b_proj = (const float*)d_in[6];
    float* out = (float*)d_out;
    char* ws = (char*)d_ws;

    // workspace layout (79.7 MB, no aliasing)
    short* xb  = (short*)(ws + 0);          // 16,777,216
    short* y   = (short*)(ws + 16777216);   // 16,777,216
    short* WpT = (short*)(ws + 33554432);   //  8,388,608
    short* Qb  = (short*)(ws + 41943040);   // 16,777,216
    short* Kb  = (short*)(ws + 58720256);   //  4,194,304
    short* VT  = (short*)(ws + 62914560);   //  4,194,304
    short* WaT = (short*)(ws + 67108864);   // 12,582,912

    prep_kernel<<<4608, 256, 0, stream>>>(x, xb, W_attn, WaT, W_proj, WpT);
    gemm_qkv<<<dim3(32, 24), 256, 0, stream>>>(xb, WaT, b_attn, fcos, fsin, Qb, Kb, VT);
    attn_kernel<<<dim3(32, 8), 512, 0, stream>>>(Qb, Kb, VT, y);
    gemm_bt<<<dim3(32, 16), 256, 0, stream>>>(y, WpT, b_proj, out, NTOK_, C_, C_);
}

// Round 17
// 213.630 us; speedup vs baseline: 1.0090x; 1.0090x over previous
//
#include <hip/hip_runtime.h>
#include <hip/hip_bf16.h>
#include <stdint.h>

#define B_ 2
#define T_ 2048
#define C_ 2048
#define NH_ 16
#define NKVH_ 4
#define HS_ 128
#define QKV_ 3072
#define NTOK_ 4096

typedef __attribute__((ext_vector_type(4))) float f32x4;
typedef __attribute__((ext_vector_type(16))) float f32x16;
typedef __attribute__((ext_vector_type(8))) short s16x8;

__device__ __forceinline__ short f2bf(float f) {
    union { float f; unsigned u; } v; v.f = f;
    unsigned r = v.u + 0x7FFFu + ((v.u >> 16) & 1u);
    return (short)(r >> 16);
}

__device__ __forceinline__ void async16(const void* g, void* l) {
    __builtin_amdgcn_global_load_lds(
        (const __attribute__((address_space(1))) void*)g,
        (__attribute__((address_space(3))) void*)l, 16, 0, 0);
}

// ---------------- fused prep: cast x->bf16 + transcast W_attn + transcast W_proj ----------------
__device__ __forceinline__ void transcast_body(const float* __restrict__ W, short* __restrict__ WT,
                                               int Kd, int Nd, int k0, int n0, int tid) {
    __shared__ float tile[64][65];
    int cl = tid & 63, rw = tid >> 6;
    for (int it = 0; it < 16; ++it) {
        int r = it * 4 + rw;
        tile[r][cl] = W[(size_t)(k0 + r) * Nd + n0 + cl];
    }
    __syncthreads();
    for (int it = 0; it < 16; ++it) {
        int n = it * 4 + rw;
        WT[(size_t)(n0 + n) * Kd + k0 + cl] = f2bf(tile[cl][n]);
    }
}

__global__ void prep_kernel(const float* __restrict__ x, short* __restrict__ xb,
                            const float* __restrict__ Wa, short* __restrict__ WaT,
                            const float* __restrict__ Wp, short* __restrict__ WpT)
{
    int bid = blockIdx.x, tid = threadIdx.x;
    if (bid < 2048) {
        const int n8 = NTOK_ * C_ / 8;
        int i0 = bid * 512 + tid;
#pragma unroll
        for (int rep = 0; rep < 2; rep++) {
            int i = i0 + rep * 256;
            if (i >= n8) return;
            const float4* p = (const float4*)x + (size_t)i * 2;
            float4 a = p[0], b = p[1];
            short o[8] = { f2bf(a.x), f2bf(a.y), f2bf(a.z), f2bf(a.w),
                           f2bf(b.x), f2bf(b.y), f2bf(b.z), f2bf(b.w) };
            *(int4*)(xb + (size_t)i * 8) = *(const int4*)o;
        }
    } else if (bid < 3584) {
        int b2 = bid - 2048;                 // 1536 blocks = 32 x 48
        transcast_body(Wa, WaT, C_, QKV_, (b2 & 31) * 64, (b2 >> 5) * 64, tid);
    } else {
        int b2 = bid - 3584;                 // 1024 blocks = 32 x 32
        transcast_body(Wp, WpT, C_, C_, (b2 & 31) * 64, (b2 >> 5) * 64, tid);
    }
}

// ---------------- GEMM: A[M][K] bf16 x Bt[N][K] bf16 -> C[M][N] f32 + bias ----------------
// XCD-aware bijective block swizzle (T1): nwg must be divisible by 8 (512 = 32x16 OK).
__global__ __launch_bounds__(256, 2) void gemm_bt(
    const short* __restrict__ A, const short* __restrict__ Bt,
    const float* __restrict__ bias, float* __restrict__ Cc,
    int M, int N, int K)
{
    __shared__ short As[128 * 64];
    __shared__ short Bs[128 * 64];
    int tid = threadIdx.x;
    int w = tid >> 6, l = tid & 63;
    int lr = l & 15, lg = l >> 4;
    int nwgx = gridDim.x;
    int wgid = blockIdx.y * nwgx + blockIdx.x;
    int q8 = (nwgx * gridDim.y) >> 3;
    int swz = (wgid & 7) * q8 + (wgid >> 3);     // bijective: nwg%8==0
    int bm = swz % nwgx, bn = swz / nwgx;
    int wm = (w >> 1) * 64, wn = (w & 1) * 64;
    f32x4 acc[4][4];
#pragma unroll
    for (int i = 0; i < 4; i++)
#pragma unroll
        for (int j = 0; j < 4; j++) { acc[i][j][0]=0.f; acc[i][j][1]=0.f; acc[i][j][2]=0.f; acc[i][j][3]=0.f; }
    int arow = l >> 3, acol = (l & 7) * 8;
    for (int k0 = 0; k0 < K; k0 += 64) {
#pragma unroll
        for (int i = 0; i < 4; i++) {
            int chunk = w * 4 + i;
            int row = chunk * 8 + arow;
            async16(A  + (size_t)(bm * 128 + row) * K + k0 + acol, (char*)As + chunk * 1024);
            async16(Bt + (size_t)(bn * 128 + row) * K + k0 + acol, (char*)Bs + chunk * 1024);
        }
        __syncthreads();
#pragma unroll
        for (int ks = 0; ks < 2; ks++) {
            s16x8 af[4], bf[4];
#pragma unroll
            for (int mi = 0; mi < 4; mi++)
                af[mi] = *(const s16x8*)&As[(wm + mi * 16 + lr) * 64 + ks * 32 + lg * 8];
#pragma unroll
            for (int ni = 0; ni < 4; ni++)
                bf[ni] = *(const s16x8*)&Bs[(wn + ni * 16 + lr) * 64 + ks * 32 + lg * 8];
#pragma unroll
            for (int mi = 0; mi < 4; mi++)
#pragma unroll
                for (int ni = 0; ni < 4; ni++)
                    acc[mi][ni] = __builtin_amdgcn_mfma_f32_16x16x32_bf16(af[mi], bf[ni], acc[mi][ni], 0, 0, 0);
        }
        __syncthreads();
    }
#pragma unroll
    for (int mi = 0; mi < 4; mi++) {
        int row = bm * 128 + wm + mi * 16 + lg * 4;
#pragma unroll
        for (int ni = 0; ni < 4; ni++) {
            int col = bn * 128 + wn + ni * 16 + lr;
            float bv = bias[col];
#pragma unroll
            for (int j = 0; j < 4; j++)
                Cc[(size_t)(row + j) * N + col] = acc[mi][ni][j] + bv;
        }
    }
}

// ---------------- Fused QKV GEMM: x_bf16 x W_attn^T + b, then RoPE + scatter in epilogue ----------
// XCD-aware bijective block swizzle (T1): nwg = 32x24 = 768, %8==0 OK.
__global__ __launch_bounds__(256, 2) void gemm_qkv(
    const short* __restrict__ A, const short* __restrict__ Bt,
    const float* __restrict__ bias,
    const float* __restrict__ fcos, const float* __restrict__ fsin,
    short* __restrict__ Q, short* __restrict__ Kb, short* __restrict__ VT)
{
    __shared__ short As[128 * 64];
    __shared__ short Bs[128 * 64];
    const int K = C_;
    int tid = threadIdx.x;
    int w = tid >> 6, l = tid & 63;
    int lr = l & 15, lg = l >> 4;
    int wgid = blockIdx.y * 32 + blockIdx.x;
    int swz = (wgid & 7) * 96 + (wgid >> 3);     // bijective: 768%8==0
    int bm = swz % 32, bn = swz / 32;
    int wm = (w >> 1) * 64, wn = (w & 1) * 64;
    f32x4 acc[4][4];
#pragma unroll
    for (int i = 0; i < 4; i++)
#pragma unroll
        for (int j = 0; j < 4; j++) { acc[i][j][0]=0.f; acc[i][j][1]=0.f; acc[i][j][2]=0.f; acc[i][j][3]=0.f; }
    int arow = l >> 3, acol = (l & 7) * 8;
    for (int k0 = 0; k0 < K; k0 += 64) {
#pragma unroll
        for (int i = 0; i < 4; i++) {
            int chunk = w * 4 + i;
            int row = chunk * 8 + arow;
            async16(A  + (size_t)(bm * 128 + row) * K + k0 + acol, (char*)As + chunk * 1024);
            async16(Bt + (size_t)(bn * 128 + row) * K + k0 + acol, (char*)Bs + chunk * 1024);
        }
        __syncthreads();
#pragma unroll
        for (int ks = 0; ks < 2; ks++) {
            s16x8 af[4], bf[4];
#pragma unroll
            for (int mi = 0; mi < 4; mi++)
                af[mi] = *(const s16x8*)&As[(wm + mi * 16 + lr) * 64 + ks * 32 + lg * 8];
#pragma unroll
            for (int ni = 0; ni < 4; ni++)
                bf[ni] = *(const s16x8*)&Bs[(wn + ni * 16 + lr) * 64 + ks * 32 + lg * 8];
#pragma unroll
            for (int mi = 0; mi < 4; mi++)
#pragma unroll
                for (int ni = 0; ni < 4; ni++)
                    acc[mi][ni] = __builtin_amdgcn_mfma_f32_16x16x32_bf16(af[mi], bf[ni], acc[mi][ni], 0, 0, 0);
        }
        __syncthreads();
    }
    // ---- fused epilogue ----
    int b = bm >> 4;                 // batch (block-uniform)
    int tt0 = (bm & 15) * 128 + wm;  // sequence pos base (+ mi*16 + lg*4 + j)
    const float qsc = 0.08838834764831845f; // 1/sqrt(128)
    if (bn < 20) {
        bool isQ = (bn < 16);
        short* Ob = isQ ? (Q + (size_t)(b * NH_ + bn) * T_ * HS_)
                        : (Kb + (size_t)(b * NKVH_ + (bn - 16)) * T_ * HS_);
        float sc = isQ ? qsc : 1.0f;
#pragma unroll
        for (int ni = 0; ni < 4; ni++) {
            int d = wn + ni * 16 + lr;           // 0..127 within head
            int i = d >> 1;
            float ssign = (d & 1) ? 1.0f : -1.0f;
            float bv = bias[bn * 128 + d];
#pragma unroll
            for (int mi = 0; mi < 4; mi++) {
                int ttb = tt0 + mi * 16 + lg * 4;
#pragma unroll
                for (int j = 0; j < 4; j++) {
                    float v = acc[mi][ni][j] + bv;
                    float prt = __shfl_xor(v, 1);
                    int tt = ttb + j;
                    float c = fcos[tt * 64 + i], s = fsin[tt * 64 + i];
                    float outv = (v * c + ssign * prt * s) * sc;
                    Ob[(size_t)tt * HS_ + d] = f2bf(outv);
                }
            }
        }
    } else {
        int g = bn - 20;
        short* Vb = VT + (size_t)(b * NKVH_ + g) * HS_ * T_;
#pragma unroll
        for (int ni = 0; ni < 4; ni++) {
            int d = wn + ni * 16 + lr;
            float bv = bias[bn * 128 + d];
#pragma unroll
            for (int mi = 0; mi < 4; mi++) {
                int ttb = tt0 + mi * 16 + lg * 4;
                short pk4[4];
#pragma unroll
                for (int j = 0; j < 4; j++) pk4[j] = f2bf(acc[mi][ni][j] + bv);
                *(int2*)(Vb + (size_t)d * T_ + ttb) = *(const int2*)pk4;
            }
        }
    }
}

// ---------------- Flash attention, causal GQA — swapped-QK^T 32x32, in-register P ----------------
// ROUND-15 KERNEL VERBATIM (best measured: 80us). ROUND-16 LESSON: 8-wave KVBLK=128 at
// 1 block/CU regressed to 92.7us — co-residency (2 blocks/CU) is worth more than barrier
// amortization; same lesson as round 11. This structure's floor is ~80us; further gains
// need the full co-designed 8-phase counted-vmcnt pipeline (not worth the risk here).
// launch_bounds(256,2): (256,4) spills (round 2). grid.x MUST be 32 (b=bh>>4, round 3).
__global__ __launch_bounds__(256, 2) void attn_kernel(
    const short* __restrict__ Qg, const short* __restrict__ Kg,
    const short* __restrict__ VTg, short* __restrict__ Y)
{
    __shared__ short Ks[2][64 * 128];   // [buf][s][d], swizzled (256B rows, XOR (row&7)<<4)
    __shared__ short VTs[2][128 * 64];  // [buf][d][s], swizzled (128B rows, XOR (row&7)<<4)
    int tid = threadIdx.x, w = tid >> 6, l = tid & 63;
    int l31 = l & 31, hi = l >> 5;
    int yy = blockIdx.y;
    int qt = (yy < 8) ? yy : 23 - yy;   // CU-complementary pairing
    int bh = blockIdx.x;
    int b = bh >> 4, h = bh & 15, g = h >> 2;
    const short* Qb = Qg + (size_t)(b * NH_ + h) * T_ * HS_;
    const short* Kb = Kg + (size_t)(b * NKVH_ + g) * T_ * HS_;
    const short* Vb = VTg + (size_t)(b * NKVH_ + g) * HS_ * T_;

    auto STAGE = [&](int st, int buf) {
#pragma unroll
        for (int i = 0; i < 4; i++) {
            int chunk = w * 4 + i;
            int poff = chunk * 1024 + l * 16;
            int qoffk = poff ^ (((poff >> 8) & 7) << 4);
            async16(Kb + (size_t)(st * 64 + (qoffk >> 8)) * HS_ + ((qoffk & 255) >> 1),
                    (char*)&Ks[buf][0] + chunk * 1024);
            int qoffv = poff ^ (((poff >> 7) & 7) << 4);
            async16(Vb + (size_t)(qoffv >> 7) * T_ + st * 64 + ((qoffv & 127) >> 1),
                    (char*)&VTs[buf][0] + chunk * 1024);
        }
    };

    int qw = qt * 128 + w * 32;      // wave's first q-row
    int qglob = qw + l31;            // this lane's q-row

    s16x8 qf[8];
#pragma unroll
    for (int dc = 0; dc < 8; dc++)
        qf[dc] = *(const s16x8*)(Qb + (size_t)qglob * HS_ + dc * 16 + hi * 8);

    f32x16 oacc[4];
#pragma unroll
    for (int db = 0; db < 4; db++)
#pragma unroll
        for (int i = 0; i < 16; i++) oacc[db][i] = 0.f;
    float m = -1e30f, lsum = 0.f;
    int nst = 2 * qt + 2;

    STAGE(0, 0);
    __syncthreads();
    int cur = 0;

    for (int st = 0; st < nst; ++st) {
        if (st + 1 < nst) STAGE(st + 1, cur ^ 1);   // K+V prefetch flies under compute
        if (st * 64 <= qw) {                        // skip fully-masked tiles (wave-uniform)
            const char* KsC = (const char*)&Ks[cur][0];
            const char* VsC = (const char*)&VTs[cur][0];

            f32x16 sacc[2];
            __builtin_amdgcn_s_setprio(1);
#pragma unroll
            for (int sb = 0; sb < 2; sb++) {
                f32x16 a0, a1;
#pragma unroll
                for (int i = 0; i < 16; i++) { a0[i] = 0.f; a1[i] = 0.f; }
#pragma unroll
                for (int dc = 0; dc < 4; dc++) {
                    int lo0 = (sb * 32 + l31) * 256 + dc * 32 + hi * 16;
                    int po0 = lo0 ^ (((lo0 >> 8) & 7) << 4);
                    s16x8 kf0 = *(const s16x8*)(KsC + po0);
                    a0 = __builtin_amdgcn_mfma_f32_32x32x16_bf16(kf0, qf[dc], a0, 0, 0, 0);
                    int lo1 = (sb * 32 + l31) * 256 + (dc + 4) * 32 + hi * 16;
                    int po1 = lo1 ^ (((lo1 >> 8) & 7) << 4);
                    s16x8 kf1 = *(const s16x8*)(KsC + po1);
                    a1 = __builtin_amdgcn_mfma_f32_32x32x16_bf16(kf1, qf[dc + 4], a1, 0, 0, 0);
                }
#pragma unroll
                for (int i = 0; i < 16; i++) a0[i] += a1[i];
                sacc[sb] = a0;
            }
            __builtin_amdgcn_s_setprio(0);
            if (st * 64 + 63 > qw) {
#pragma unroll
                for (int sb = 0; sb < 2; sb++)
#pragma unroll
                    for (int r = 0; r < 16; r++) {
                        int s = st * 64 + sb * 32 + (r & 3) + 8 * (r >> 2) + 4 * hi;
                        if (s > qglob) sacc[sb][r] = -1e30f;
                    }
            }
            float tm = -1e30f;
#pragma unroll
            for (int sb = 0; sb < 2; sb++)
#pragma unroll
                for (int r = 0; r < 16; r++) tm = fmaxf(tm, sacc[sb][r]);
            tm = fmaxf(tm, __shfl_xor(tm, 32));
            if (__any(tm > m)) {
                float mn = fmaxf(m, tm);
                float corr = __expf(m - mn);
                m = mn; lsum *= corr;
#pragma unroll
                for (int db = 0; db < 4; db++)
#pragma unroll
                    for (int r = 0; r < 16; r++) oacc[db][r] *= corr;
            }
            // P = exp(S^T - m), packed in-register
            unsigned w01[2][4], w23[2][4];
#pragma unroll
            for (int sb = 0; sb < 2; sb++)
#pragma unroll
                for (int k = 0; k < 4; k++) {
                    float p0 = __expf(sacc[sb][4 * k]     - m);
                    float p1 = __expf(sacc[sb][4 * k + 1] - m);
                    float p2 = __expf(sacc[sb][4 * k + 2] - m);
                    float p3 = __expf(sacc[sb][4 * k + 3] - m);
                    lsum += (p0 + p1) + (p2 + p3);
                    w01[sb][k] = (unsigned)(unsigned short)f2bf(p0) | ((unsigned)(unsigned short)f2bf(p1) << 16);
                    w23[sb][k] = (unsigned)(unsigned short)f2bf(p2) | ((unsigned)(unsigned short)f2bf(p3) << 16);
                }
            // O^T += V^T · P ; PV B-operand assembled via cross-half shfl (no LDS)
            __builtin_amdgcn_s_setprio(1);
#pragma unroll
            for (int sc = 0; sc < 4; sc++) {
                const int sb = sc >> 1;
                const int k0 = (2 * sc) & 3, k1 = k0 + 1;
                unsigned ownA = hi ? w01[sb][k1] : w01[sb][k0];
                unsigned ownB = hi ? w23[sb][k1] : w23[sb][k0];
                unsigned sndA = hi ? w01[sb][k0] : w01[sb][k1];   // word the partner needs
                unsigned sndB = hi ? w23[sb][k0] : w23[sb][k1];
                unsigned rcvA = (unsigned)__shfl_xor((int)sndA, 32);
                unsigned rcvB = (unsigned)__shfl_xor((int)sndB, 32);
                unsigned uu[4];
                uu[0] = hi ? rcvA : ownA;
                uu[1] = hi ? rcvB : ownB;
                uu[2] = hi ? ownA : rcvA;
                uu[3] = hi ? ownB : rcvB;
                s16x8 pf = *(const s16x8*)uu;
#pragma unroll
                for (int db = 0; db < 4; db++) {
                    int lo = (db * 32 + l31) * 128 + sc * 32 + hi * 16;
                    int po = lo ^ (((lo >> 7) & 7) << 4);
                    s16x8 vf = *(const s16x8*)(VsC + po);
                    oacc[db] = __builtin_amdgcn_mfma_f32_32x32x16_bf16(vf, pf, oacc[db], 0, 0, 0);
                }
            }
            __builtin_amdgcn_s_setprio(0);
        }
        __syncthreads();
        cur ^= 1;
    }

    lsum += __shfl_xor(lsum, 32);
    float inv = 1.0f / lsum;
    short* Yrow = Y + (size_t)(b * T_ + qglob) * C_ + h * 128;
#pragma unroll
    for (int db = 0; db < 4; db++)
#pragma unroll
        for (int pr = 0; pr < 8; pr++) {
            unsigned u0 = (unsigned short)f2bf(oacc[db][2 * pr] * inv);
            unsigned u1 = (unsigned short)f2bf(oacc[db][2 * pr + 1] * inv);
            int d = db * 32 + ((2 * pr) & 3) + 8 * (pr >> 1) + 4 * hi;
            *(unsigned*)(Yrow + d) = u0 | (u1 << 16);
        }
}

extern "C" void kernel_launch(void* const* d_in, const int* in_sizes, int n_in,
                              void* d_out, int out_size, void* d_ws, size_t ws_size,
                              hipStream_t stream)
{
    const float* x      = (const float*)d_in[0];
    const float* fcos   = (const float*)d_in[1];
    const float* fsin   = (const float*)d_in[2];
    const float* W_attn = (const float*)d_in[3];
    const float* b_attn = (const float*)d_in[4];
    const float* W_proj = (const float*)d_in[5];
    const float* b_proj = (const float*)d_in[6];
    float* out = (float*)d_out;
    char* ws = (char*)d_ws;

    // workspace layout (79.7 MB, no aliasing)
    short* xb  = (short*)(ws + 0);          // 16,777,216
    short* y   = (short*)(ws + 16777216);   // 16,777,216
    short* WpT = (short*)(ws + 33554432);   //  8,388,608
    short* Qb  = (short*)(ws + 41943040);   // 16,777,216
    short* Kb  = (short*)(ws + 58720256);   //  4,194,304
    short* VT  = (short*)(ws + 62914560);   //  4,194,304
    short* WaT = (short*)(ws + 67108864);   // 12,582,912

    prep_kernel<<<4608, 256, 0, stream>>>(x, xb, W_attn, WaT, W_proj, WpT);
    gemm_qkv<<<dim3(32, 24), 256, 0, stream>>>(xb, WaT, b_attn, fcos, fsin, Qb, Kb, VT);
    attn_kernel<<<dim3(32, 16), 256, 0, stream>>>(Qb, Kb, VT, y);
    gemm_bt<<<dim3(32, 16), 256, 0, stream>>>(y, WpT, b_proj, out, NTOK_, C_, C_);
}

// Round 18
// 202.916 us; speedup vs baseline: 1.0622x; 1.0528x over previous
//
#include <hip/hip_runtime.h>
#include <hip/hip_bf16.h>
#include <stdint.h>

#define B_ 2
#define T_ 2048
#define C_ 2048
#define NH_ 16
#define NKVH_ 4
#define HS_ 128
#define QKV_ 3072
#define NTOK_ 4096

typedef __attribute__((ext_vector_type(4))) float f32x4;
typedef __attribute__((ext_vector_type(16))) float f32x16;
typedef __attribute__((ext_vector_type(8))) short s16x8;

__device__ __forceinline__ short f2bf(float f) {
    union { float f; unsigned u; } v; v.f = f;
    unsigned r = v.u + 0x7FFFu + ((v.u >> 16) & 1u);
    return (short)(r >> 16);
}

__device__ __forceinline__ void async16(const void* g, void* l) {
    __builtin_amdgcn_global_load_lds(
        (const __attribute__((address_space(1))) void*)g,
        (__attribute__((address_space(3))) void*)l, 16, 0, 0);
}

// ---------------- fused prep: cast x->bf16 + transcast W_attn + transcast W_proj ----------------
__device__ __forceinline__ void transcast_body(const float* __restrict__ W, short* __restrict__ WT,
                                               int Kd, int Nd, int k0, int n0, int tid) {
    __shared__ float tile[64][65];
    int cl = tid & 63, rw = tid >> 6;
    for (int it = 0; it < 16; ++it) {
        int r = it * 4 + rw;
        tile[r][cl] = W[(size_t)(k0 + r) * Nd + n0 + cl];
    }
    __syncthreads();
    for (int it = 0; it < 16; ++it) {
        int n = it * 4 + rw;
        WT[(size_t)(n0 + n) * Kd + k0 + cl] = f2bf(tile[cl][n]);
    }
}

__global__ void prep_kernel(const float* __restrict__ x, short* __restrict__ xb,
                            const float* __restrict__ Wa, short* __restrict__ WaT,
                            const float* __restrict__ Wp, short* __restrict__ WpT)
{
    int bid = blockIdx.x, tid = threadIdx.x;
    if (bid < 2048) {
        const int n8 = NTOK_ * C_ / 8;
        int i0 = bid * 512 + tid;
#pragma unroll
        for (int rep = 0; rep < 2; rep++) {
            int i = i0 + rep * 256;
            if (i >= n8) return;
            const float4* p = (const float4*)x + (size_t)i * 2;
            float4 a = p[0], b = p[1];
            short o[8] = { f2bf(a.x), f2bf(a.y), f2bf(a.z), f2bf(a.w),
                           f2bf(b.x), f2bf(b.y), f2bf(b.z), f2bf(b.w) };
            *(int4*)(xb + (size_t)i * 8) = *(const int4*)o;
        }
    } else if (bid < 3584) {
        int b2 = bid - 2048;                 // 1536 blocks = 32 x 48
        transcast_body(Wa, WaT, C_, QKV_, (b2 & 31) * 64, (b2 >> 5) * 64, tid);
    } else {
        int b2 = bid - 3584;                 // 1024 blocks = 32 x 32
        transcast_body(Wp, WpT, C_, C_, (b2 & 31) * 64, (b2 >> 5) * 64, tid);
    }
}

// ---------------- GEMM: A[M][K] bf16 x Bt[N][K] bf16 -> C[M][N] f32 + bias ----------------
// NO XCD swizzle: default x-major dispatch already shares the B-panel within each XCD
// (round-17: swizzle exploded per-XCD A-footprint 2MB->16.8MB, FETCH 102MB, +10us).
__global__ __launch_bounds__(256, 2) void gemm_bt(
    const short* __restrict__ A, const short* __restrict__ Bt,
    const float* __restrict__ bias, float* __restrict__ Cc,
    int M, int N, int K)
{
    __shared__ short As[128 * 64];
    __shared__ short Bs[128 * 64];
    int tid = threadIdx.x;
    int w = tid >> 6, l = tid & 63;
    int lr = l & 15, lg = l >> 4;
    int bm = blockIdx.x, bn = blockIdx.y;
    int wm = (w >> 1) * 64, wn = (w & 1) * 64;
    f32x4 acc[4][4];
#pragma unroll
    for (int i = 0; i < 4; i++)
#pragma unroll
        for (int j = 0; j < 4; j++) { acc[i][j][0]=0.f; acc[i][j][1]=0.f; acc[i][j][2]=0.f; acc[i][j][3]=0.f; }
    int arow = l >> 3, acol = (l & 7) * 8;
    for (int k0 = 0; k0 < K; k0 += 64) {
#pragma unroll
        for (int i = 0; i < 4; i++) {
            int chunk = w * 4 + i;
            int row = chunk * 8 + arow;
            async16(A  + (size_t)(bm * 128 + row) * K + k0 + acol, (char*)As + chunk * 1024);
            async16(Bt + (size_t)(bn * 128 + row) * K + k0 + acol, (char*)Bs + chunk * 1024);
        }
        __syncthreads();
#pragma unroll
        for (int ks = 0; ks < 2; ks++) {
            s16x8 af[4], bf[4];
#pragma unroll
            for (int mi = 0; mi < 4; mi++)
                af[mi] = *(const s16x8*)&As[(wm + mi * 16 + lr) * 64 + ks * 32 + lg * 8];
#pragma unroll
            for (int ni = 0; ni < 4; ni++)
                bf[ni] = *(const s16x8*)&Bs[(wn + ni * 16 + lr) * 64 + ks * 32 + lg * 8];
#pragma unroll
            for (int mi = 0; mi < 4; mi++)
#pragma unroll
                for (int ni = 0; ni < 4; ni++)
                    acc[mi][ni] = __builtin_amdgcn_mfma_f32_16x16x32_bf16(af[mi], bf[ni], acc[mi][ni], 0, 0, 0);
        }
        __syncthreads();
    }
#pragma unroll
    for (int mi = 0; mi < 4; mi++) {
        int row = bm * 128 + wm + mi * 16 + lg * 4;
#pragma unroll
        for (int ni = 0; ni < 4; ni++) {
            int col = bn * 128 + wn + ni * 16 + lr;
            float bv = bias[col];
#pragma unroll
            for (int j = 0; j < 4; j++)
                Cc[(size_t)(row + j) * N + col] = acc[mi][ni][j] + bv;
        }
    }
}

// ---------------- Fused QKV GEMM: x_bf16 x W_attn^T + b, then RoPE + scatter in epilogue ----------
__global__ __launch_bounds__(256, 2) void gemm_qkv(
    const short* __restrict__ A, const short* __restrict__ Bt,
    const float* __restrict__ bias,
    const float* __restrict__ fcos, const float* __restrict__ fsin,
    short* __restrict__ Q, short* __restrict__ Kb, short* __restrict__ VT)
{
    __shared__ short As[128 * 64];
    __shared__ short Bs[128 * 64];
    const int K = C_;
    int tid = threadIdx.x;
    int w = tid >> 6, l = tid & 63;
    int lr = l & 15, lg = l >> 4;
    int bm = blockIdx.x, bn = blockIdx.y;
    int wm = (w >> 1) * 64, wn = (w & 1) * 64;
    f32x4 acc[4][4];
#pragma unroll
    for (int i = 0; i < 4; i++)
#pragma unroll
        for (int j = 0; j < 4; j++) { acc[i][j][0]=0.f; acc[i][j][1]=0.f; acc[i][j][2]=0.f; acc[i][j][3]=0.f; }
    int arow = l >> 3, acol = (l & 7) * 8;
    for (int k0 = 0; k0 < K; k0 += 64) {
#pragma unroll
        for (int i = 0; i < 4; i++) {
            int chunk = w * 4 + i;
            int row = chunk * 8 + arow;
            async16(A  + (size_t)(bm * 128 + row) * K + k0 + acol, (char*)As + chunk * 1024);
            async16(Bt + (size_t)(bn * 128 + row) * K + k0 + acol, (char*)Bs + chunk * 1024);
        }
        __syncthreads();
#pragma unroll
        for (int ks = 0; ks < 2; ks++) {
            s16x8 af[4], bf[4];
#pragma unroll
            for (int mi = 0; mi < 4; mi++)
                af[mi] = *(const s16x8*)&As[(wm + mi * 16 + lr) * 64 + ks * 32 + lg * 8];
#pragma unroll
            for (int ni = 0; ni < 4; ni++)
                bf[ni] = *(const s16x8*)&Bs[(wn + ni * 16 + lr) * 64 + ks * 32 + lg * 8];
#pragma unroll
            for (int mi = 0; mi < 4; mi++)
#pragma unroll
                for (int ni = 0; ni < 4; ni++)
                    acc[mi][ni] = __builtin_amdgcn_mfma_f32_16x16x32_bf16(af[mi], bf[ni], acc[mi][ni], 0, 0, 0);
        }
        __syncthreads();
    }
    // ---- fused epilogue ----
    int b = bm >> 4;                 // batch (block-uniform)
    int tt0 = (bm & 15) * 128 + wm;  // sequence pos base (+ mi*16 + lg*4 + j)
    const float qsc = 0.08838834764831845f; // 1/sqrt(128)
    if (bn < 20) {
        bool isQ = (bn < 16);
        short* Ob = isQ ? (Q + (size_t)(b * NH_ + bn) * T_ * HS_)
                        : (Kb + (size_t)(b * NKVH_ + (bn - 16)) * T_ * HS_);
        float sc = isQ ? qsc : 1.0f;
#pragma unroll
        for (int ni = 0; ni < 4; ni++) {
            int d = wn + ni * 16 + lr;           // 0..127 within head
            int i = d >> 1;
            float ssign = (d & 1) ? 1.0f : -1.0f;
            float bv = bias[bn * 128 + d];
#pragma unroll
            for (int mi = 0; mi < 4; mi++) {
                int ttb = tt0 + mi * 16 + lg * 4;
#pragma unroll
                for (int j = 0; j < 4; j++) {
                    float v = acc[mi][ni][j] + bv;
                    float prt = __shfl_xor(v, 1);
                    int tt = ttb + j;
                    float c = fcos[tt * 64 + i], s = fsin[tt * 64 + i];
                    float outv = (v * c + ssign * prt * s) * sc;
                    Ob[(size_t)tt * HS_ + d] = f2bf(outv);
                }
            }
        }
    } else {
        int g = bn - 20;
        short* Vb = VT + (size_t)(b * NKVH_ + g) * HS_ * T_;
#pragma unroll
        for (int ni = 0; ni < 4; ni++) {
            int d = wn + ni * 16 + lr;
            float bv = bias[bn * 128 + d];
#pragma unroll
            for (int mi = 0; mi < 4; mi++) {
                int ttb = tt0 + mi * 16 + lg * 4;
                short pk4[4];
#pragma unroll
                for (int j = 0; j < 4; j++) pk4[j] = f2bf(acc[mi][ni][j] + bv);
                *(int2*)(Vb + (size_t)d * T_ + ttb) = *(const int2*)pk4;
            }
        }
    }
}

// ---------------- Flash attention, causal GQA — swapped-QK^T 32x32, in-register P ----------------
// Best measured attn: ~80us. Structure floor (LPT / pairing / CU-pair / V-global / big-tile
// variants all 80-93us). launch_bounds(256,2); grid.x MUST be 32 (b=bh>>4).
__global__ __launch_bounds__(256, 2) void attn_kernel(
    const short* __restrict__ Qg, const short* __restrict__ Kg,
    const short* __restrict__ VTg, short* __restrict__ Y)
{
    __shared__ short Ks[2][64 * 128];   // [buf][s][d], swizzled (256B rows, XOR (row&7)<<4)
    __shared__ short VTs[2][128 * 64];  // [buf][d][s], swizzled (128B rows, XOR (row&7)<<4)
    int tid = threadIdx.x, w = tid >> 6, l = tid & 63;
    int l31 = l & 31, hi = l >> 5;
    int yy = blockIdx.y;
    int qt = (yy < 8) ? yy : 23 - yy;   // CU-complementary pairing
    int bh = blockIdx.x;
    int b = bh >> 4, h = bh & 15, g = h >> 2;
    const short* Qb = Qg + (size_t)(b * NH_ + h) * T_ * HS_;
    const short* Kb = Kg + (size_t)(b * NKVH_ + g) * T_ * HS_;
    const short* Vb = VTg + (size_t)(b * NKVH_ + g) * HS_ * T_;

    auto STAGE = [&](int st, int buf) {
#pragma unroll
        for (int i = 0; i < 4; i++) {
            int chunk = w * 4 + i;
            int poff = chunk * 1024 + l * 16;
            int qoffk = poff ^ (((poff >> 8) & 7) << 4);
            async16(Kb + (size_t)(st * 64 + (qoffk >> 8)) * HS_ + ((qoffk & 255) >> 1),
                    (char*)&Ks[buf][0] + chunk * 1024);
            int qoffv = poff ^ (((poff >> 7) & 7) << 4);
            async16(Vb + (size_t)(qoffv >> 7) * T_ + st * 64 + ((qoffv & 127) >> 1),
                    (char*)&VTs[buf][0] + chunk * 1024);
        }
    };

    int qw = qt * 128 + w * 32;      // wave's first q-row
    int qglob = qw + l31;            // this lane's q-row

    s16x8 qf[8];
#pragma unroll
    for (int dc = 0; dc < 8; dc++)
        qf[dc] = *(const s16x8*)(Qb + (size_t)qglob * HS_ + dc * 16 + hi * 8);

    f32x16 oacc[4];
#pragma unroll
    for (int db = 0; db < 4; db++)
#pragma unroll
        for (int i = 0; i < 16; i++) oacc[db][i] = 0.f;
    float m = -1e30f, lsum = 0.f;
    int nst = 2 * qt + 2;

    STAGE(0, 0);
    __syncthreads();
    int cur = 0;

    for (int st = 0; st < nst; ++st) {
        if (st + 1 < nst) STAGE(st + 1, cur ^ 1);   // K+V prefetch flies under compute
        if (st * 64 <= qw) {                        // skip fully-masked tiles (wave-uniform)
            const char* KsC = (const char*)&Ks[cur][0];
            const char* VsC = (const char*)&VTs[cur][0];

            f32x16 sacc[2];
            __builtin_amdgcn_s_setprio(1);
#pragma unroll
            for (int sb = 0; sb < 2; sb++) {
                f32x16 a0, a1;
#pragma unroll
                for (int i = 0; i < 16; i++) { a0[i] = 0.f; a1[i] = 0.f; }
#pragma unroll
                for (int dc = 0; dc < 4; dc++) {
                    int lo0 = (sb * 32 + l31) * 256 + dc * 32 + hi * 16;
                    int po0 = lo0 ^ (((lo0 >> 8) & 7) << 4);
                    s16x8 kf0 = *(const s16x8*)(KsC + po0);
                    a0 = __builtin_amdgcn_mfma_f32_32x32x16_bf16(kf0, qf[dc], a0, 0, 0, 0);
                    int lo1 = (sb * 32 + l31) * 256 + (dc + 4) * 32 + hi * 16;
                    int po1 = lo1 ^ (((lo1 >> 8) & 7) << 4);
                    s16x8 kf1 = *(const s16x8*)(KsC + po1);
                    a1 = __builtin_amdgcn_mfma_f32_32x32x16_bf16(kf1, qf[dc + 4], a1, 0, 0, 0);
                }
#pragma unroll
                for (int i = 0; i < 16; i++) a0[i] += a1[i];
                sacc[sb] = a0;
            }
            __builtin_amdgcn_s_setprio(0);
            if (st * 64 + 63 > qw) {
#pragma unroll
                for (int sb = 0; sb < 2; sb++)
#pragma unroll
                    for (int r = 0; r < 16; r++) {
                        int s = st * 64 + sb * 32 + (r & 3) + 8 * (r >> 2) + 4 * hi;
                        if (s > qglob) sacc[sb][r] = -1e30f;
                    }
            }
            float tm = -1e30f;
#pragma unroll
            for (int sb = 0; sb < 2; sb++)
#pragma unroll
                for (int r = 0; r < 16; r++) tm = fmaxf(tm, sacc[sb][r]);
            tm = fmaxf(tm, __shfl_xor(tm, 32));
            if (__any(tm > m)) {
                float mn = fmaxf(m, tm);
                float corr = __expf(m - mn);
                m = mn; lsum *= corr;
#pragma unroll
                for (int db = 0; db < 4; db++)
#pragma unroll
                    for (int r = 0; r < 16; r++) oacc[db][r] *= corr;
            }
            // P = exp(S^T - m), packed in-register
            unsigned w01[2][4], w23[2][4];
#pragma unroll
            for (int sb = 0; sb < 2; sb++)
#pragma unroll
                for (int k = 0; k < 4; k++) {
                    float p0 = __expf(sacc[sb][4 * k]     - m);
                    float p1 = __expf(sacc[sb][4 * k + 1] - m);
                    float p2 = __expf(sacc[sb][4 * k + 2] - m);
                    float p3 = __expf(sacc[sb][4 * k + 3] - m);
                    lsum += (p0 + p1) + (p2 + p3);
                    w01[sb][k] = (unsigned)(unsigned short)f2bf(p0) | ((unsigned)(unsigned short)f2bf(p1) << 16);
                    w23[sb][k] = (unsigned)(unsigned short)f2bf(p2) | ((unsigned)(unsigned short)f2bf(p3) << 16);
                }
            // O^T += V^T · P ; PV B-operand assembled via cross-half shfl (no LDS)
            __builtin_amdgcn_s_setprio(1);
#pragma unroll
            for (int sc = 0; sc < 4; sc++) {
                const int sb = sc >> 1;
                const int k0 = (2 * sc) & 3, k1 = k0 + 1;
                unsigned ownA = hi ? w01[sb][k1] : w01[sb][k0];
                unsigned ownB = hi ? w23[sb][k1] : w23[sb][k0];
                unsigned sndA = hi ? w01[sb][k0] : w01[sb][k1];   // word the partner needs
                unsigned sndB = hi ? w23[sb][k0] : w23[sb][k1];
                unsigned rcvA = (unsigned)__shfl_xor((int)sndA, 32);
                unsigned rcvB = (unsigned)__shfl_xor((int)sndB, 32);
                unsigned uu[4];
                uu[0] = hi ? rcvA : ownA;
                uu[1] = hi ? rcvB : ownB;
                uu[2] = hi ? ownA : rcvA;
                uu[3] = hi ? ownB : rcvB;
                s16x8 pf = *(const s16x8*)uu;
#pragma unroll
                for (int db = 0; db < 4; db++) {
                    int lo = (db * 32 + l31) * 128 + sc * 32 + hi * 16;
                    int po = lo ^ (((lo >> 7) & 7) << 4);
                    s16x8 vf = *(const s16x8*)(VsC + po);
                    oacc[db] = __builtin_amdgcn_mfma_f32_32x32x16_bf16(vf, pf, oacc[db], 0, 0, 0);
                }
            }
            __builtin_amdgcn_s_setprio(0);
        }
        __syncthreads();
        cur ^= 1;
    }

    lsum += __shfl_xor(lsum, 32);
    float inv = 1.0f / lsum;
    short* Yrow = Y + (size_t)(b * T_ + qglob) * C_ + h * 128;
#pragma unroll
    for (int db = 0; db < 4; db++)
#pragma unroll
        for (int pr = 0; pr < 8; pr++) {
            unsigned u0 = (unsigned short)f2bf(oacc[db][2 * pr] * inv);
            unsigned u1 = (unsigned short)f2bf(oacc[db][2 * pr + 1] * inv);
            int d = db * 32 + ((2 * pr) & 3) + 8 * (pr >> 1) + 4 * hi;
            *(unsigned*)(Yrow + d) = u0 | (u1 << 16);
        }
}

extern "C" void kernel_launch(void* const* d_in, const int* in_sizes, int n_in,
                              void* d_out, int out_size, void* d_ws, size_t ws_size,
                              hipStream_t stream)
{
    const float* x      = (const float*)d_in[0];
    const float* fcos   = (const float*)d_in[1];
    const float* fsin   = (const float*)d_in[2];
    const float* W_attn = (const float*)d_in[3];
    const float* b_attn = (const float*)d_in[4];
    const float* W_proj = (const float*)d_in[5];
    const float* b_proj = (const float*)d_in[6];
    float* out = (float*)d_out;
    char* ws = (char*)d_ws;

    // workspace layout (79.7 MB, no aliasing)
    short* xb  = (short*)(ws + 0);          // 16,777,216
    short* y   = (short*)(ws + 16777216);   // 16,777,216
    short* WpT = (short*)(ws + 33554432);   //  8,388,608
    short* Qb  = (short*)(ws + 41943040);   // 16,777,216
    short* Kb  = (short*)(ws + 58720256);   //  4,194,304
    short* VT  = (short*)(ws + 62914560);   //  4,194,304
    short* WaT = (short*)(ws + 67108864);   // 12,582,912

    prep_kernel<<<4608, 256, 0, stream>>>(x, xb, W_attn, WaT, W_proj, WpT);
    gemm_qkv<<<dim3(32, 24), 256, 0, stream>>>(xb, WaT, b_attn, fcos, fsin, Qb, Kb, VT);
    attn_kernel<<<dim3(32, 16), 256, 0, stream>>>(Qb, Kb, VT, y);
    gemm_bt<<<dim3(32, 16), 256, 0, stream>>>(y, WpT, b_proj, out, NTOK_, C_, C_);
}